// Round 5
// baseline (433.772 us; speedup 1.0000x reference)
//
#include <hip/hip_runtime.h>

// T=2000 tags, V=20000 videos, D=768, E_POS=E_NEG=100000
// Outputs (fp32, concat): cls_score [V,T], labels [V,T]
//
// Round 5: same one-block-per-video fused structure as round 4, but the
// feature matrices are converted ONCE per call to bf16 in d_ws:
//   - tag working set 6.1 -> 3.0 MB  => fits 4 MB per-XCD L2 (gather at L2 BW)
//   - per-edge gather bytes halve (3 KB -> 1.5 KB)
// Dot products unpack bf16->fp32 in registers and accumulate in fp32.

#define T_DIM 2000
#define V_DIM 20000
#define D_DIM 768
#define EPOS  100000
#define ENEG  100000
#define ETOT  (EPOS + ENEG)

#define CAP   96   // max edges per video; Poisson(mean=10), P(>96) ~ 1e-33

// d_ws layout:
//   int    cursor[V_DIM]                      @ 0
//   int    packed[V_DIM*CAP]                  @ V_DIM ints
//   ushort tag16 [T_DIM*D_DIM]                @ byte 7,760,000
//   ushort vid16 [V_DIM*D_DIM]                @ byte 10,832,000
#define WS_PACKED_I  V_DIM
#define WS_TAG16_B   7760000
#define WS_VID16_B   10832000

__device__ __forceinline__ ushort f2bf(float x)   // round-to-nearest-even
{
    unsigned u = __float_as_uint(x);
    u += 0x7FFFu + ((u >> 16) & 1u);
    return (ushort)(u >> 16);
}

__device__ __forceinline__ void unpack4(uint2 u, float* f)
{
    f[0] = __uint_as_float(u.x << 16);
    f[1] = __uint_as_float(u.x & 0xFFFF0000u);
    f[2] = __uint_as_float(u.y << 16);
    f[3] = __uint_as_float(u.y & 0xFFFF0000u);
}

// ---------------- K0: fp32 -> bf16 convert (float4 -> ushort4) -------------
__global__ __launch_bounds__(256) void k0_convert(
    const float4* __restrict__ in, ushort4* __restrict__ out, int n4)
{
    const int i = blockIdx.x * 256 + threadIdx.x;
    if (i >= n4) return;
    const float4 v = in[i];
    ushort4 o;
    o.x = f2bf(v.x); o.y = f2bf(v.y); o.z = f2bf(v.z); o.w = f2bf(v.w);
    out[i] = o;
}

// ---------------- K1: zero bucket cursors ----------------
__global__ __launch_bounds__(256) void k1_zero(int* ws)
{
    const int i = blockIdx.x * 256 + threadIdx.x;
    if (i < V_DIM) ws[i] = 0;
}

// ---------------- K2: scatter edges into per-video buckets ----------------
__global__ __launch_bounds__(256) void k2_bucket(
    const int* __restrict__ pos_src,
    const int* __restrict__ pos_dst,
    const int* __restrict__ neg_src,
    const int* __restrict__ neg_dst,
    int* ws)
{
    const int e = blockIdx.x * 256 + threadIdx.x;
    if (e >= ETOT) return;
    const int src = (e < EPOS) ? pos_src[e] : neg_src[e - EPOS];
    const int dst = (e < EPOS) ? pos_dst[e] : neg_dst[e - EPOS];
    const int slot = atomicAdd(&ws[dst], 1);
    if (slot < CAP)   // src fits in 16 bits (T=2000); bit16 = is_pos
        ws[WS_PACKED_I + dst * CAP + slot] = src | ((e < EPOS) ? 0x10000 : 0);
}

// ---------------- K3: fused dot + row writer, one block per video ----------
__global__ __launch_bounds__(256) void k3_fused(
    const ushort* __restrict__ tag16,
    const ushort* __restrict__ vid16,
    const int*    __restrict__ ws,
    float*        __restrict__ cls_score,
    float*        __restrict__ labels)
{
    __shared__ float lds_cls[T_DIM];
    __shared__ float lds_lab[T_DIM];

    const int v    = blockIdx.x;
    const int tid  = threadIdx.x;
    const int lane = tid & 63;
    const int wave = tid >> 6;          // 4 waves per block

    for (int i = tid; i < T_DIM; i += 256) {
        lds_cls[i] = 0.0f;
        lds_lab[i] = 0.0f;
    }

    const int cnt = min(ws[v], CAP);

    // video row once: 768 bf16 = 192 uint2 across 64 lanes = 3 uint2/lane
    const uint2* b2 = (const uint2*)(vid16 + (size_t)v * D_DIM);
    float b[12];
    unpack4(b2[lane],       b + 0);
    unpack4(b2[lane + 64],  b + 4);
    unpack4(b2[lane + 128], b + 8);

    __syncthreads();   // LDS zero complete before atomics

    const int* pk = ws + WS_PACKED_I + v * CAP;
    for (int k = wave; k < cnt; k += 4) {
        const int p   = pk[k];
        const int src = p & 0xFFFF;

        const uint2* a2 = (const uint2*)(tag16 + (size_t)src * D_DIM);
        const uint2 A0 = a2[lane];
        const uint2 A1 = a2[lane + 64];
        const uint2 A2 = a2[lane + 128];

        float a[12];
        unpack4(A0, a + 0);
        unpack4(A1, a + 4);
        unpack4(A2, a + 8);

        float acc = 0.0f;
#pragma unroll
        for (int j = 0; j < 12; ++j)
            acc = fmaf(a[j], b[j], acc);

#pragma unroll
        for (int off = 32; off >= 1; off >>= 1)
            acc += __shfl_xor(acc, off, 64);

        if (lane == 0) {
            atomicAdd(&lds_cls[src], acc);          // LDS atomic (duplicates)
            if (p & 0x10000)
                atomicAdd(&lds_lab[src], 1.0f);
        }
    }

    __syncthreads();   // all scores landed in LDS

    float4*       oc  = (float4*)(cls_score + (size_t)v * T_DIM);
    float4*       ol  = (float4*)(labels    + (size_t)v * T_DIM);
    const float4* s4c = (const float4*)lds_cls;
    const float4* s4l = (const float4*)lds_lab;
    for (int i = tid; i < T_DIM / 4; i += 256) {   // 500 float4 per row
        oc[i] = s4c[i];
        ol[i] = s4l[i];
    }
}

extern "C" void kernel_launch(void* const* d_in, const int* in_sizes, int n_in,
                              void* d_out, int out_size, void* d_ws, size_t ws_size,
                              hipStream_t stream)
{
    const float* h_tag   = (const float*)d_in[0];
    const float* h_video = (const float*)d_in[1];
    const int*   pos_src = (const int*)d_in[2];
    const int*   pos_dst = (const int*)d_in[3];
    const int*   neg_src = (const int*)d_in[4];
    const int*   neg_dst = (const int*)d_in[5];

    float* cls_score = (float*)d_out;                          // [V, T]
    float* labels    = (float*)d_out + (size_t)V_DIM * T_DIM;  // [V, T]
    int*   ws        = (int*)d_ws;
    ushort* tag16    = (ushort*)((char*)d_ws + WS_TAG16_B);
    ushort* vid16    = (ushort*)((char*)d_ws + WS_VID16_B);

    const int n4_tag = T_DIM * D_DIM / 4;   // 384,000
    const int n4_vid = V_DIM * D_DIM / 4;   // 3,840,000

    k0_convert<<<(n4_tag + 255) / 256, 256, 0, stream>>>(
        (const float4*)h_tag, (ushort4*)tag16, n4_tag);
    k0_convert<<<(n4_vid + 255) / 256, 256, 0, stream>>>(
        (const float4*)h_video, (ushort4*)vid16, n4_vid);

    k1_zero<<<(V_DIM + 255) / 256, 256, 0, stream>>>(ws);

    k2_bucket<<<(ETOT + 255) / 256, 256, 0, stream>>>(
        pos_src, pos_dst, neg_src, neg_dst, ws);

    k3_fused<<<V_DIM, 256, 0, stream>>>(
        tag16, vid16, ws, cls_score, labels);
}

// Round 6
// 421.034 us; speedup vs baseline: 1.0303x; 1.0303x over previous
//
#include <hip/hip_runtime.h>

// T=2000 tags, V=20000 videos, D=768, E_POS=E_NEG=100000
// Outputs (fp32, concat): cls_score [V,T], labels [V,T]
//
// Round 6 structure:
//   K0: convert tags (only) to bf16 -> 3 MB, L2-resident gather target
//   K1: zero bucket cursors
//   K2: bucket edges by dst video (fixed CAP, no scan)
//   K3: ONE WAVE PER VIDEO, barrier-free: video row (fp32) once in regs,
//       bucket prefetched + __shfl-broadcast, bf16 tag gather, butterfly
//       reduce, lane k keeps edge k's score, one coalesced score store.
//   K4: ONE BLOCK PER VIDEO, pure writer: coalesced bucket+score load,
//       LDS scatter (atomics for duplicate edges), stream 16 KB out.

#define T_DIM 2000
#define V_DIM 20000
#define D_DIM 768
#define EPOS  100000
#define ENEG  100000
#define ETOT  (EPOS + ENEG)

#define CAP   96   // binomial(200k,1/20k): P(any bucket > 64) ~ 1e-24

// d_ws layout (int indices):
#define WS_CURSOR 0
#define WS_PACKED 20480                       // V_DIM*CAP ints
#define WS_SCORES (20480 + V_DIM * CAP)       // V_DIM*CAP floats
#define WS_TAG16  (WS_SCORES + V_DIM * CAP)   // T_DIM*D_DIM ushorts

__device__ __forceinline__ ushort f2bf(float x)   // round-to-nearest-even
{
    unsigned u = __float_as_uint(x);
    u += 0x7FFFu + ((u >> 16) & 1u);
    return (ushort)(u >> 16);
}

__device__ __forceinline__ void unpack4(uint2 u, float* f)
{
    f[0] = __uint_as_float(u.x << 16);
    f[1] = __uint_as_float(u.x & 0xFFFF0000u);
    f[2] = __uint_as_float(u.y << 16);
    f[3] = __uint_as_float(u.y & 0xFFFF0000u);
}

// ---------------- K0: tag fp32 -> bf16 ----------------
__global__ __launch_bounds__(256) void k0_convert_tag(
    const float4* __restrict__ in, ushort4* __restrict__ out, int n4)
{
    const int i = blockIdx.x * 256 + threadIdx.x;
    if (i >= n4) return;
    const float4 v = in[i];
    ushort4 o;
    o.x = f2bf(v.x); o.y = f2bf(v.y); o.z = f2bf(v.z); o.w = f2bf(v.w);
    out[i] = o;
}

// ---------------- K1: zero bucket cursors ----------------
__global__ __launch_bounds__(256) void k1_zero(int* ws)
{
    const int i = blockIdx.x * 256 + threadIdx.x;
    if (i < V_DIM) ws[WS_CURSOR + i] = 0;
}

// ---------------- K2: bucket edges by dst ----------------
__global__ __launch_bounds__(256) void k2_bucket(
    const int* __restrict__ pos_src,
    const int* __restrict__ pos_dst,
    const int* __restrict__ neg_src,
    const int* __restrict__ neg_dst,
    int* ws)
{
    const int e = blockIdx.x * 256 + threadIdx.x;
    if (e >= ETOT) return;
    const int src = (e < EPOS) ? pos_src[e] : neg_src[e - EPOS];
    const int dst = (e < EPOS) ? pos_dst[e] : neg_dst[e - EPOS];
    const int slot = atomicAdd(&ws[WS_CURSOR + dst], 1);
    if (slot < CAP)   // src fits in 16 bits (T=2000); bit16 = is_pos
        ws[WS_PACKED + dst * CAP + slot] = src | ((e < EPOS) ? 0x10000 : 0);
}

// ---------------- K3: one wave per video, barrier-free dots ----------------
__global__ __launch_bounds__(256) void k3_dots(
    const float*  __restrict__ h_video,
    const ushort* __restrict__ tag16,
    int*          __restrict__ ws)
{
    const int lane = threadIdx.x & 63;
    const int v    = blockIdx.x * 4 + (threadIdx.x >> 6);
    if (v >= V_DIM) return;

    const int cnt = min(ws[WS_CURSOR + v], CAP);
    if (cnt == 0) return;

    // fp32 video row once: 192 float4 across 64 lanes = 3/lane
    const float4* b4 = (const float4*)(h_video + (size_t)v * D_DIM);
    const float4 b0 = b4[lane];
    const float4 b1 = b4[lane + 64];
    const float4 b2 = b4[lane + 128];

    const int*  pk = ws + WS_PACKED + v * CAP;
    float*      sc = (float*)(ws + WS_SCORES) + v * CAP;

    const int pre = (lane < cnt) ? pk[lane] : 0;   // coalesced bucket prefetch
    float myscore = 0.0f;

    for (int k = 0; k < cnt; ++k) {
        const int p   = (k < 64) ? __shfl(pre, k, 64) : pk[k];
        const int src = p & 0xFFFF;

        const uint2* a2 = (const uint2*)(tag16 + (size_t)src * D_DIM);
        const uint2 A0 = a2[lane];
        const uint2 A1 = a2[lane + 64];
        const uint2 A2 = a2[lane + 128];

        float a[12];
        unpack4(A0, a + 0);
        unpack4(A1, a + 4);
        unpack4(A2, a + 8);

        float acc = 0.0f;
        acc = fmaf(a[0],  b0.x, acc); acc = fmaf(a[1],  b0.y, acc);
        acc = fmaf(a[2],  b0.z, acc); acc = fmaf(a[3],  b0.w, acc);
        acc = fmaf(a[4],  b1.x, acc); acc = fmaf(a[5],  b1.y, acc);
        acc = fmaf(a[6],  b1.z, acc); acc = fmaf(a[7],  b1.w, acc);
        acc = fmaf(a[8],  b2.x, acc); acc = fmaf(a[9],  b2.y, acc);
        acc = fmaf(a[10], b2.z, acc); acc = fmaf(a[11], b2.w, acc);

#pragma unroll
        for (int off = 32; off >= 1; off >>= 1)
            acc += __shfl_xor(acc, off, 64);       // all lanes hold sum

        if (k == lane) myscore = acc;              // lane k keeps edge k
        if (k >= 64 && lane == 0) sc[k] = acc;     // cold path (never hit)
    }

    if (lane < cnt && lane < 64)
        sc[lane] = myscore;                        // one coalesced store
}

// ---------------- K4: one block per video, pure row writer ----------------
__global__ __launch_bounds__(256) void k4_write(
    const int* __restrict__ ws,
    float*     __restrict__ cls_score,
    float*     __restrict__ labels)
{
    __shared__ float lds_cls[T_DIM];
    __shared__ float lds_lab[T_DIM];

    const int v   = blockIdx.x;
    const int tid = threadIdx.x;

    for (int i = tid; i < T_DIM; i += 256) {
        lds_cls[i] = 0.0f;
        lds_lab[i] = 0.0f;
    }

    const int cnt = min(ws[WS_CURSOR + v], CAP);
    __syncthreads();

    if (tid < cnt) {                               // cnt <= 96 < 256
        const int   p   = ws[WS_PACKED + v * CAP + tid];
        const float s   = ((const float*)(ws + WS_SCORES))[v * CAP + tid];
        const int   src = p & 0xFFFF;
        atomicAdd(&lds_cls[src], s);               // duplicates handled
        if (p & 0x10000)
            atomicAdd(&lds_lab[src], 1.0f);
    }
    __syncthreads();

    float4*       oc  = (float4*)(cls_score + (size_t)v * T_DIM);
    float4*       ol  = (float4*)(labels    + (size_t)v * T_DIM);
    const float4* s4c = (const float4*)lds_cls;
    const float4* s4l = (const float4*)lds_lab;
    for (int i = tid; i < T_DIM / 4; i += 256) {   // 500 float4 per row
        oc[i] = s4c[i];
        ol[i] = s4l[i];
    }
}

extern "C" void kernel_launch(void* const* d_in, const int* in_sizes, int n_in,
                              void* d_out, int out_size, void* d_ws, size_t ws_size,
                              hipStream_t stream)
{
    const float* h_tag   = (const float*)d_in[0];
    const float* h_video = (const float*)d_in[1];
    const int*   pos_src = (const int*)d_in[2];
    const int*   pos_dst = (const int*)d_in[3];
    const int*   neg_src = (const int*)d_in[4];
    const int*   neg_dst = (const int*)d_in[5];

    float*  cls_score = (float*)d_out;                          // [V, T]
    float*  labels    = (float*)d_out + (size_t)V_DIM * T_DIM;  // [V, T]
    int*    ws        = (int*)d_ws;
    ushort* tag16     = (ushort*)(ws + WS_TAG16);

    const int n4_tag = T_DIM * D_DIM / 4;   // 384,000

    k0_convert_tag<<<(n4_tag + 255) / 256, 256, 0, stream>>>(
        (const float4*)h_tag, (ushort4*)tag16, n4_tag);

    k1_zero<<<(V_DIM + 255) / 256, 256, 0, stream>>>(ws);

    k2_bucket<<<(ETOT + 255) / 256, 256, 0, stream>>>(
        pos_src, pos_dst, neg_src, neg_dst, ws);

    k3_dots<<<(V_DIM + 3) / 4, 256, 0, stream>>>(h_video, tag16, ws);

    k4_write<<<V_DIM, 256, 0, stream>>>(ws, cls_score, labels);
}

// Round 7
// 413.531 us; speedup vs baseline: 1.0489x; 1.0181x over previous
//
#include <hip/hip_runtime.h>

// T=2000 tags, V=20000 videos, D=768, E_POS=E_NEG=100000
// Outputs (fp32, concat): cls_score [V,T], labels [V,T]
//
// Round 7 = round 6 structure + latency fixes:
//   KA: fused [tag fp32->bf16 convert] + [zero bucket cursors]
//   K2: bucket edges by dst video (fixed CAP)
//   K3: one wave per video, 2-edge pipelined dot chains, NT video loads
//   K4: one block per video, early bucket/score loads, NT output stores

#define T_DIM 2000
#define V_DIM 20000
#define D_DIM 768
#define EPOS  100000
#define ENEG  100000
#define ETOT  (EPOS + ENEG)

#define CAP   96

// d_ws layout (int indices):
#define WS_CURSOR 0
#define WS_PACKED 20480                       // V_DIM*CAP ints
#define WS_SCORES (20480 + V_DIM * CAP)       // V_DIM*CAP floats
#define WS_TAG16  (WS_SCORES + V_DIM * CAP)   // T_DIM*D_DIM ushorts

typedef float vfloat4 __attribute__((ext_vector_type(4)));

__device__ __forceinline__ ushort f2bf(float x)   // round-to-nearest-even
{
    unsigned u = __float_as_uint(x);
    u += 0x7FFFu + ((u >> 16) & 1u);
    return (ushort)(u >> 16);
}

__device__ __forceinline__ void unpack4(uint2 u, float* f)
{
    f[0] = __uint_as_float(u.x << 16);
    f[1] = __uint_as_float(u.x & 0xFFFF0000u);
    f[2] = __uint_as_float(u.y << 16);
    f[3] = __uint_as_float(u.y & 0xFFFF0000u);
}

// ---------------- KA: tag convert + cursor zero (fused) ----------------
__global__ __launch_bounds__(256) void ka_init(
    const vfloat4* __restrict__ tag_in, ushort4* __restrict__ tag16, int* ws)
{
    const int i = blockIdx.x * 256 + threadIdx.x;
    if (i < T_DIM * D_DIM / 4) {
        const vfloat4 v = __builtin_nontemporal_load(&tag_in[i]);
        ushort4 o;
        o.x = f2bf(v.x); o.y = f2bf(v.y); o.z = f2bf(v.z); o.w = f2bf(v.w);
        tag16[i] = o;
    }
    if (i < V_DIM) ws[WS_CURSOR + i] = 0;
}

// ---------------- K2: bucket edges by dst ----------------
__global__ __launch_bounds__(256) void k2_bucket(
    const int* __restrict__ pos_src,
    const int* __restrict__ pos_dst,
    const int* __restrict__ neg_src,
    const int* __restrict__ neg_dst,
    int* ws)
{
    const int e = blockIdx.x * 256 + threadIdx.x;
    if (e >= ETOT) return;
    const int src = (e < EPOS) ? pos_src[e] : neg_src[e - EPOS];
    const int dst = (e < EPOS) ? pos_dst[e] : neg_dst[e - EPOS];
    const int slot = atomicAdd(&ws[WS_CURSOR + dst], 1);
    if (slot < CAP)   // src fits in 16 bits (T=2000); bit16 = is_pos
        ws[WS_PACKED + dst * CAP + slot] = src | ((e < EPOS) ? 0x10000 : 0);
}

// ---------------- K3: one wave per video, 2-edge pipelined dots -----------
__device__ __forceinline__ float edge_dot(
    const ushort* tag16, int src, int lane, const float* b)
{
    const uint2* a2 = (const uint2*)(tag16 + (size_t)src * D_DIM);
    const uint2 A0 = a2[lane];
    const uint2 A1 = a2[lane + 64];
    const uint2 A2 = a2[lane + 128];
    float a[12];
    unpack4(A0, a + 0);
    unpack4(A1, a + 4);
    unpack4(A2, a + 8);
    float acc = 0.0f;
#pragma unroll
    for (int j = 0; j < 12; ++j)
        acc = fmaf(a[j], b[j], acc);
    return acc;
}

__global__ __launch_bounds__(256) void k3_dots(
    const float*  __restrict__ h_video,
    const ushort* __restrict__ tag16,
    int*          __restrict__ ws)
{
    const int lane = threadIdx.x & 63;
    const int v    = blockIdx.x * 4 + (threadIdx.x >> 6);
    if (v >= V_DIM) return;

    const int cnt = min(ws[WS_CURSOR + v], CAP);
    if (cnt == 0) return;

    // fp32 video row once, nontemporal (streamed exactly once; keep tag16 in L2)
    const vfloat4* b4 = (const vfloat4*)(h_video + (size_t)v * D_DIM);
    const vfloat4 B0 = __builtin_nontemporal_load(&b4[lane]);
    const vfloat4 B1 = __builtin_nontemporal_load(&b4[lane + 64]);
    const vfloat4 B2 = __builtin_nontemporal_load(&b4[lane + 128]);
    float b[12] = {B0.x, B0.y, B0.z, B0.w,
                   B1.x, B1.y, B1.z, B1.w,
                   B2.x, B2.y, B2.z, B2.w};

    const int* pk = ws + WS_PACKED + v * CAP;
    float*     sc = (float*)(ws + WS_SCORES) + v * CAP;

    const int pre = (lane < cnt) ? pk[lane] : 0;   // coalesced bucket prefetch
    float myscore = 0.0f;

    int k = 0;
    const int pair_end = min(cnt, 64) & ~1;
    for (; k < pair_end; k += 2) {                 // two independent chains
        const int p0 = __shfl(pre, k,     64);
        const int p1 = __shfl(pre, k + 1, 64);
        float acc0 = edge_dot(tag16, p0 & 0xFFFF, lane, b);
        float acc1 = edge_dot(tag16, p1 & 0xFFFF, lane, b);
#pragma unroll
        for (int off = 32; off >= 1; off >>= 1) {  // interleaved butterflies
            acc0 += __shfl_xor(acc0, off, 64);
            acc1 += __shfl_xor(acc1, off, 64);
        }
        if (lane == k)     myscore = acc0;
        if (lane == k + 1) myscore = acc1;
    }
    for (; k < cnt; ++k) {                         // tail + (cold) k>=64 path
        const int p = (k < 64) ? __shfl(pre, k, 64) : pk[k];
        float acc = edge_dot(tag16, p & 0xFFFF, lane, b);
#pragma unroll
        for (int off = 32; off >= 1; off >>= 1)
            acc += __shfl_xor(acc, off, 64);
        if (lane == k) myscore = acc;
        if (k >= 64 && lane == 0) sc[k] = acc;
    }

    if (lane < cnt && lane < 64)
        sc[lane] = myscore;                        // one coalesced store
}

// ---------------- K4: one block per video, pure row writer ----------------
__global__ __launch_bounds__(256) void k4_write(
    const int* __restrict__ ws,
    float*     __restrict__ cls_score,
    float*     __restrict__ labels)
{
    __shared__ float lds_cls[T_DIM];
    __shared__ float lds_lab[T_DIM];

    const int v   = blockIdx.x;
    const int tid = threadIdx.x;

    // issue data loads FIRST so they overlap the LDS zeroing
    const int cnt = min(ws[WS_CURSOR + v], CAP);
    int   p = 0;
    float s = 0.0f;
    if (tid < CAP) {
        p = ws[WS_PACKED + v * CAP + tid];
        s = ((const float*)(ws + WS_SCORES))[v * CAP + tid];
    }

    for (int i = tid; i < T_DIM; i += 256) {
        lds_cls[i] = 0.0f;
        lds_lab[i] = 0.0f;
    }
    __syncthreads();

    if (tid < cnt) {                               // cnt <= 96 < 256
        const int src = p & 0xFFFF;
        atomicAdd(&lds_cls[src], s);               // duplicates handled
        if (p & 0x10000)
            atomicAdd(&lds_lab[src], 1.0f);
    }
    __syncthreads();

    vfloat4*       oc  = (vfloat4*)(cls_score + (size_t)v * T_DIM);
    vfloat4*       ol  = (vfloat4*)(labels    + (size_t)v * T_DIM);
    const vfloat4* s4c = (const vfloat4*)lds_cls;
    const vfloat4* s4l = (const vfloat4*)lds_lab;
    for (int i = tid; i < T_DIM / 4; i += 256) {   // 500 vfloat4 per row
        __builtin_nontemporal_store(s4c[i], &oc[i]);
        __builtin_nontemporal_store(s4l[i], &ol[i]);
    }
}

extern "C" void kernel_launch(void* const* d_in, const int* in_sizes, int n_in,
                              void* d_out, int out_size, void* d_ws, size_t ws_size,
                              hipStream_t stream)
{
    const float* h_tag   = (const float*)d_in[0];
    const float* h_video = (const float*)d_in[1];
    const int*   pos_src = (const int*)d_in[2];
    const int*   pos_dst = (const int*)d_in[3];
    const int*   neg_src = (const int*)d_in[4];
    const int*   neg_dst = (const int*)d_in[5];

    float*  cls_score = (float*)d_out;                          // [V, T]
    float*  labels    = (float*)d_out + (size_t)V_DIM * T_DIM;  // [V, T]
    int*    ws        = (int*)d_ws;
    ushort* tag16     = (ushort*)(ws + WS_TAG16);

    const int n4_tag = T_DIM * D_DIM / 4;   // 384,000

    ka_init<<<(n4_tag + 255) / 256, 256, 0, stream>>>(
        (const vfloat4*)h_tag, (ushort4*)tag16, ws);

    k2_bucket<<<(ETOT + 255) / 256, 256, 0, stream>>>(
        pos_src, pos_dst, neg_src, neg_dst, ws);

    k3_dots<<<(V_DIM + 3) / 4, 256, 0, stream>>>(h_video, tag16, ws);

    k4_write<<<V_DIM, 256, 0, stream>>>(ws, cls_score, labels);
}